// Round 1
// baseline (4076.222 us; speedup 1.0000x reference)
//
#include <hip/hip_runtime.h>
#include <hip/hip_bf16.h>

using bf16 = __hip_bfloat16;
typedef __attribute__((ext_vector_type(8))) short s8v;   // 8 bf16 (4 VGPR)
typedef __attribute__((ext_vector_type(4))) float f4v;   // 4 fp32 acc

static __device__ __forceinline__ float bf2f(bf16 v){ return __bfloat162float(v); }
static __device__ __forceinline__ bf16 f2bf(float v){ return __float2bfloat16(v); }
static __device__ __forceinline__ float sigm(float x){ return 1.f/(1.f+expf(-x)); }

// ---------------------------------------------------------------------------
// Generic conv-GEMM: A = padded channel-last images (IMG,9x9,rowC) bf16,
// im2col done via per-lane address gather (k = tap*Cin + ci).
// B = weights [N][9*Cin] bf16, k-order tap*Cin+ci. Output: fp32 partial slice.
// Tile 128x128, BK=64, 4 waves (2x2), mfma_f32_16x16x32_bf16.
// ---------------------------------------------------------------------------
__global__ __launch_bounds__(256)
void kgemm(const bf16* __restrict__ Ab, const bf16* __restrict__ Bw,
           int Cin, int rowC, int chOff, int Mvalid, int Ktot, int kLen,
           float* __restrict__ Cout, int ldC, long sliceStride)
{
  __shared__ __align__(16) bf16 As[128*64];
  __shared__ __align__(16) bf16 Bs[128*64];
  const int tid = threadIdx.x;
  const int m0 = blockIdx.x*128, n0 = blockIdx.y*128;
  const int k0 = blockIdx.z*kLen;
  const int kc = (tid & 7)*8;

  long aRowEl[4]; const bf16* bPtr[4];
  #pragma unroll
  for (int j=0;j<4;++j){
    int r = j*32 + (tid>>3);
    int m = m0 + r; if (m > Mvalid-1) m = Mvalid-1;
    int img = m/49; int hw = m - img*49; int h = hw/7; int w = hw - h*7;
    long pix = (long)img*81 + (h+1)*9 + (w+1);
    aRowEl[j] = pix*(long)rowC + chOff + kc;
    bPtr[j] = Bw + (long)(n0 + r)*Ktot + k0 + kc;
  }

  f4v acc[4][4] = {};
  const int lane = tid & 63;
  const int wv = tid >> 6;
  const int wr = (wv>>1)*64, wc = (wv&1)*64;
  const int fr = lane & 15, fg = lane >> 4;

  int tap = k0 / Cin;
  int ci0 = k0 - tap*Cin;
  const int nSteps = kLen >> 6;

  for (int ks=0; ks<nSteps; ++ks){
    int tdv = tap + 6*(tap/3) - 10;              // (kh-1)*9 + (kw-1)
    long aOff = (long)tdv*rowC + ci0;
    uint4 av[4], bv[4];
    #pragma unroll
    for (int j=0;j<4;++j){
      av[j] = *(const uint4*)(Ab + (aRowEl[j] + aOff));
      bv[j] = *(const uint4*)(bPtr[j]);
      bPtr[j] += 64;
    }
    __syncthreads();
    #pragma unroll
    for (int j=0;j<4;++j){
      *(uint4*)(&As[(j*256+tid)*8]) = av[j];
      *(uint4*)(&Bs[(j*256+tid)*8]) = bv[j];
    }
    __syncthreads();
    #pragma unroll
    for (int kk=0;kk<2;++kk){
      s8v af[4], bfr[4];
      #pragma unroll
      for (int mt=0;mt<4;++mt) af[mt]  = *(const s8v*)(&As[(wr+mt*16+fr)*64 + kk*32 + fg*8]);
      #pragma unroll
      for (int nt=0;nt<4;++nt) bfr[nt] = *(const s8v*)(&Bs[(wc+nt*16+fr)*64 + kk*32 + fg*8]);
      #pragma unroll
      for (int mt=0;mt<4;++mt)
        #pragma unroll
        for (int nt=0;nt<4;++nt)
          acc[mt][nt] = __builtin_amdgcn_mfma_f32_16x16x32_bf16(af[mt], bfr[nt], acc[mt][nt], 0,0,0);
    }
    ci0 += 64; if (ci0 >= Cin){ ci0 = 0; ++tap; }
  }

  float* Cp = Cout + (long)blockIdx.z*sliceStride;
  #pragma unroll
  for (int mt=0;mt<4;++mt){
    #pragma unroll
    for (int j=0;j<4;++j){
      int m = m0 + wr + mt*16 + fg*4 + j;        // C/D: row=(lane>>4)*4+reg
      if (m < Mvalid){
        float* row = Cp + (long)m*ldC + n0 + wc;
        #pragma unroll
        for (int nt=0;nt<4;++nt) row[nt*16 + fr] = acc[mt][nt][j];   // col=lane&15
      }
    }
  }
}

// fp32 [co][ci][3][3] -> bf16 [co][tap*Cin+ci]
__global__ void kwconv(const float* __restrict__ src, bf16* __restrict__ dst,
                       int N, int Cin, int srcStride, int srcOff)
{
  long i = (long)blockIdx.x*256 + threadIdx.x;
  long total = (long)N*Cin*9;
  if (i >= total) return;
  int cin9 = Cin*9;
  int n = (int)(i / cin9);
  int r = (int)(i - (long)n*cin9);
  int tap = r / Cin;
  int ci = r - tap*Cin;
  dst[i] = f2bf(src[(long)n*srcStride + srcOff + ci*9 + tap]);
}

// BN scale/shift precompute for the 6 param sets
__global__ void kbnprep(const float* mk1, const float* mk2, const float* hb1,
                        const float* cb1, const float* hb2, const float* cb2,
                        float* ss)
{
  int i = blockIdx.x*256 + threadIdx.x;
  if (i >= 4608) return;
  const float* p; int C, c, so, sho;
  if (i < 1024)      { p=mk1; C=1024; c=i;       so=0;    sho=1024; }
  else if (i < 1536) { p=mk2; C=512;  c=i-1024;  so=2048; sho=2560; }
  else if (i < 2560) { p=hb1; C=1024; c=i-1536;  so=3072; sho=5120; }
  else if (i < 3584) { p=cb1; C=1024; c=i-2560;  so=4096; sho=6144; }
  else if (i < 4096) { p=hb2; C=512;  c=i-3584;  so=7168; sho=7680; }
  else               { p=cb2; C=512;  c=i-4096;  so=8192; sho=8704; }
  float g=p[c], b=p[C+c], m=p[2*C+c], v=p[3*C+c];
  float s = g * rsqrtf(v + 1e-5f);
  ss[so + c] = s;
  ss[sho + c] = b - m*s;
}

// x (2,2048,22,7,7) fp32 -> xtp (44,81,2048) bf16 padded channel-last
__global__ void kxtp(const float* __restrict__ x, bf16* __restrict__ xtp)
{
  int idx = blockIdx.x*256 + threadIdx.x;   // 44*81*2048 exact
  int ci = idx & 2047;
  int rest = idx >> 11;
  int hwp = rest % 81;
  int bt = rest / 81;
  int h9 = hwp/9, w9 = hwp - h9*9;
  float v = 0.f;
  if (h9>=1 && h9<=7 && w9>=1 && w9<=7){
    int b = bt/22, t = bt - b*22;
    v = x[((long)(b*2048+ci)*22 + t)*49 + (h9-1)*7 + (w9-1)];
  }
  xtp[idx] = f2bf(v);
}

// sum two partial slices + BN + relu -> padded channel-last bf16 image
__global__ void kbnpack(const float* __restrict__ C0, const float* __restrict__ C1,
                        const float* __restrict__ scale, const float* __restrict__ shift,
                        int N, int Mvalid, bf16* __restrict__ outImg, int outRowC)
{
  int idx = blockIdx.x*256 + threadIdx.x;
  if (idx >= Mvalid*N) return;
  int m = idx / N, n = idx - m*N;
  float v = C0[idx] + C1[idx];
  v = fmaxf(fmaf(v, scale[n], shift[n]), 0.f);
  int img = m/49, hw = m - img*49;
  int h = hw/7, w = hw - h*7;
  outImg[((long)img*81 + (h+1)*9 + (w+1))*outRowC + n] = f2bf(v);
}

// mask conv3 (512->1) + sigmoid; writes mask buffer and d_out mask section
__global__ void kmask3(const bf16* __restrict__ a2p, const float* __restrict__ w3,
                       float* __restrict__ maskb, float* __restrict__ outMask)
{
  __shared__ float red[256];
  int bid = blockIdx.x;                 // 2156 = bt*49+hw
  int bt = bid/49, hw = bid - bt*49;
  int h = hw/7, w = hw - h*7;
  int tid = threadIdx.x;
  float s = 0.f;
  for (int k = tid; k < 4608; k += 256){
    int tap = k >> 9, ci = k & 511;
    int pix = (h + tap/3)*9 + (w + (tap - (tap/3)*3));
    s += bf2f(a2p[((long)bt*81 + pix)*512 + ci]) * w3[ci*9 + tap];
  }
  red[tid] = s; __syncthreads();
  for (int off=128; off>0; off>>=1){ if (tid<off) red[tid]+=red[tid+off]; __syncthreads(); }
  if (tid==0){
    float mv = 1.f/(1.f + expf(-red[0]));
    maskb[bid] = mv;
    outMask[bid] = mv;
  }
}

// scale xtp in place by mask -> mxp (borders stay 0)
__global__ void kmxp(bf16* __restrict__ xtp, const float* __restrict__ maskb)
{
  int idx = blockIdx.x*256 + threadIdx.x;
  int rest = idx >> 11;
  int hwp = rest % 81;
  int bt = rest / 81;
  int h9 = hwp/9, w9 = hwp - h9*9;
  if (h9<1||h9>7||w9<1||w9>7) return;
  float mv = maskb[bt*49 + (h9-1)*7 + (w9-1)];
  xtp[idx] = f2bf(bf2f(xtp[idx]) * mv);
}

// mean over T of mxp -> mxmp (2,81,2048) bf16
__global__ void kmxmp(const bf16* __restrict__ mxp, bf16* __restrict__ mxmp)
{
  int idx = blockIdx.x*256 + threadIdx.x;   // 2*81*2048 exact
  int ci = idx & 2047;
  int rest = idx >> 11;
  int hwp = rest % 81;
  int b = rest / 81;
  float s = 0.f;
  #pragma unroll
  for (int t=0;t<22;++t)
    s += bf2f(mxp[((long)(b*22+t)*81 + hwp)*2048 + ci]);
  mxmp[idx] = f2bf(s * (1.f/22.f));
}

// att_fea[b][t] = (1/49) sum_{c,hw} mask*x*wf  (fp32 from originals)
__global__ void kattfea(const float* __restrict__ x, const float* __restrict__ wf,
                        const float* __restrict__ maskb, float* __restrict__ attf)
{
  __shared__ float red[256];
  int bt = blockIdx.x; int b = bt/22, t = bt - b*22;
  int tid = threadIdx.x;
  float s = 0.f;
  for (int c=tid;c<2048;c+=256){
    const float* xp = x + ((long)(b*2048+c)*22 + t)*49;
    const float* mp = maskb + bt*49;
    float inner = 0.f;
    #pragma unroll
    for (int hw=0;hw<49;++hw) inner += mp[hw]*xp[hw];
    s += inner * wf[c];
  }
  red[tid] = s; __syncthreads();
  for (int off=128; off>0; off>>=1){ if (tid<off) red[tid]+=red[tid+off]; __syncthreads(); }
  if (tid==0) attf[bt] = red[0] * (1.f/49.f);
}

// Gx slice reduce: Gx += Gx_slice1
__global__ void kredgx(float* __restrict__ Gx)
{
  int idx = blockIdx.x*256 + threadIdx.x;   // 2156*2048 exact
  Gx[idx] += Gx[(long)2176*2048 + idx];
}

// reduce splitK slices + BN + relu; mode0: pack padded img; mode1: + hmean; mode2: flat fp32
__global__ void kredpack(const float* __restrict__ P, int slices, long sstride,
                         int N, const float* __restrict__ scale, const float* __restrict__ shift,
                         bf16* __restrict__ outImg, int outRowC,
                         float* __restrict__ outFlat, float* __restrict__ hmeanOut, int mode)
{
  int idx = blockIdx.x*256 + threadIdx.x;   // 98*N exact
  int m = idx / N, n = idx - m*N;
  float v = 0.f;
  for (int s=0;s<slices;++s) v += P[(long)s*sstride + idx];
  v = fmaxf(fmaf(v, scale[n], shift[n]), 0.f);
  if (mode == 2){ outFlat[idx] = v; return; }
  int img = m/49, hw = m - img*49;
  int h = hw/7, w = hw - h*7;
  outImg[((long)img*81 + (h+1)*9 + (w+1))*outRowC + n] = f2bf(v);
  if (mode == 1) atomicAdd(&hmeanOut[img*512 + n], v*(1.f/49.f));
}

// attention weights: att_h from hmean, softmax over T; zero next hmean slot
__global__ void kaw(const float* __restrict__ hmC, float* __restrict__ hmN,
                    const float* __restrict__ wh, const float* __restrict__ attf,
                    float* __restrict__ awbuf, float* __restrict__ awsOut)
{
  int tid = threadIdx.x;  // 64
  float a0=0.f, a1=0.f;
  for (int c=tid;c<512;c+=64){ float w=wh[c]; a0 += hmC[c]*w; a1 += hmC[512+c]*w; }
  #pragma unroll
  for (int off=32;off>0;off>>=1){ a0 += __shfl_down(a0, off); a1 += __shfl_down(a1, off); }
  __shared__ float ah[2];
  if (tid==0){ ah[0]=a0; ah[1]=a1; }
  __syncthreads();
  if (tid < 2){
    float av = ah[tid];
    float lo[22]; float mx = -1e30f;
    #pragma unroll
    for (int t=0;t<22;++t){ lo[t] = attf[tid*22+t] + av; mx = fmaxf(mx, lo[t]); }
    float sum=0.f;
    #pragma unroll
    for (int t=0;t<22;++t){ lo[t] = expf(lo[t]-mx); sum += lo[t]; }
    float inv = 1.f/sum;
    #pragma unroll
    for (int t=0;t<22;++t){ float a = lo[t]*inv; awbuf[tid*22+t] = a; awsOut[tid*22+t] = a; }
  }
  for (int i=tid;i<1024;i+=64) hmN[i] = 0.f;
}

// gates_x = lstm_b + sum_t aw_t * Gx_t   (layout [b][hw][2048])
__global__ void k1(const float* __restrict__ Gx, const float* __restrict__ awbuf,
                   const float* __restrict__ lstmb, float* __restrict__ gatesx)
{
  int idx = blockIdx.x*256 + threadIdx.x;   // 2*49*2048 exact
  int n = idx & 2047;
  int rest = idx >> 11;
  int hw = rest % 49;
  int b = rest / 49;
  float g = lstmb[n];
  const float* gp = Gx + ((long)b*22*49 + hw)*2048 + n;
  #pragma unroll
  for (int t=0;t<22;++t) g += awbuf[b*22+t] * gp[(long)t*49*2048];
  gatesx[idx] = g;
}

// LSTM pointwise: gates = gates_x + sum of 8 Wh-partials; update c, h; accum means
__global__ void k3(const float* __restrict__ gatesx, const float* __restrict__ P,
                   float* __restrict__ cstate, bf16* __restrict__ hp,
                   float* __restrict__ hmN, float* __restrict__ outs)
{
  int idx = blockIdx.x*256 + threadIdx.x;   // 2*49*512 exact
  int c = idx & 511;
  int rest = idx >> 9;
  int hw = rest % 49;
  int b = rest / 49;
  long mbase = (long)(b*49 + hw)*2048;
  float gi = gatesx[mbase + c],        gf = gatesx[mbase + 512 + c],
        go = gatesx[mbase + 1024 + c], gg = gatesx[mbase + 1536 + c];
  #pragma unroll
  for (int s=0;s<8;++s){
    const float* Ps = P + (long)s*98*2048 + mbase;
    gi += Ps[c]; gf += Ps[512+c]; go += Ps[1024+c]; gg += Ps[1536+c];
  }
  float iv = sigm(gi), fv = sigm(gf), ov = sigm(go), gv = tanhf(gg);
  float cn = fv*cstate[idx] + iv*gv;
  cstate[idx] = cn;
  float h2 = ov*tanhf(cn);
  int h = hw/7, w = hw - h*7;
  hp[((long)b*81 + (h+1)*9 + (w+1))*512 + c] = f2bf(h2);
  atomicAdd(&hmN[b*512 + c], h2*(1.f/49.f));
  atomicAdd(&outs[b*512 + c], h2*(1.f/(49.f*22.f)));
}

// final fc + zero losses
__global__ void kfinal(const float* __restrict__ outs, const float* __restrict__ fc_w,
                       const float* __restrict__ fc_b, float* __restrict__ dout)
{
  int tid = threadIdx.x;
  for (int o=tid;o<202;o+=256){
    int b = o/101, j = o - b*101;
    float s = fc_b[j];
    const float* wrow = fc_w + j*512;
    const float* ov = outs + b*512;
    for (int c=0;c<512;++c) s += ov[c]*wrow[c];
    dout[o] = s;
  }
  if (tid==0){ dout[2402]=0.f; dout[2403]=0.f; }
}

extern "C" void kernel_launch(void* const* d_in, const int* in_sizes, int n_in,
                              void* d_out, int out_size, void* d_ws, size_t ws_size,
                              hipStream_t stream)
{
  (void)in_sizes; (void)n_in; (void)out_size;
  const float* x     = (const float*)d_in[0];
  const float* wf    = (const float*)d_in[1];
  const float* wh    = (const float*)d_in[2];
  const float* fc_w  = (const float*)d_in[3];
  const float* fc_b  = (const float*)d_in[4];
  const float* h0w1  = (const float*)d_in[5];
  const float* h0bn1 = (const float*)d_in[6];
  const float* h0w2  = (const float*)d_in[7];
  const float* h0bn2 = (const float*)d_in[8];
  const float* c0w1  = (const float*)d_in[9];
  const float* c0bn1 = (const float*)d_in[10];
  const float* c0w2  = (const float*)d_in[11];
  const float* c0bn2 = (const float*)d_in[12];
  const float* mkw1  = (const float*)d_in[13];
  const float* mkbn1 = (const float*)d_in[14];
  const float* mkw2  = (const float*)d_in[15];
  const float* mkbn2 = (const float*)d_in[16];
  const float* mkw3  = (const float*)d_in[17];
  const float* lstmw = (const float*)d_in[18];
  const float* lstmb = (const float*)d_in[19];
  float* dout = (float*)d_out;

  char* base = (char*)d_ws;
  size_t off = 0;
  auto alloc = [&](size_t bytes)->void*{
    void* p = base + off;
    off = (off + bytes + 255) & ~(size_t)255;
    return p;
  };
  // --- zero span (memset once per call) ---
  bf16*  a1p   = (bf16*) alloc((size_t)44*81*1024*2);
  bf16*  a2p   = (bf16*) alloc((size_t)44*81*512*2);
  bf16*  hc1p  = (bf16*) alloc((size_t)2*81*2048*2);
  bf16*  hp    = (bf16*) alloc((size_t)2*81*512*2);
  float* hmean = (float*)alloc((size_t)2*1024*4);
  float* outsS = (float*)alloc((size_t)1024*4);
  size_t zlen = off;
  // --- rest ---
  bf16*  WmkA  = (bf16*) alloc((size_t)1024*18432*2);
  bf16*  WmkB  = (bf16*) alloc((size_t)512*9216*2);
  bf16*  Whc1  = (bf16*) alloc((size_t)2048*18432*2);
  bf16*  Wh0b  = (bf16*) alloc((size_t)512*9216*2);
  bf16*  Wc0b  = (bf16*) alloc((size_t)512*9216*2);
  bf16*  Wx    = (bf16*) alloc((size_t)2048*18432*2);
  bf16*  Whh   = (bf16*) alloc((size_t)2048*4608*2);
  bf16*  xtp   = (bf16*) alloc((size_t)44*81*2048*2);
  bf16*  mxmp  = (bf16*) alloc((size_t)2*81*2048*2);
  float* Gx    = (float*)alloc((size_t)2*2176*2048*4);
  float* Cb1   = (float*)alloc((size_t)2*2176*1024*4);
  float* Cb2   = (float*)alloc((size_t)2*2176*512*4);
  float* Pbuf  = (float*)alloc((size_t)16*98*2048*4);
  float* maskb = (float*)alloc((size_t)2156*4);
  float* gatesx= (float*)alloc((size_t)98*2048*4);
  float* attf  = (float*)alloc((size_t)64*4);
  float* cstate= (float*)alloc((size_t)98*512*4);
  float* awbuf = (float*)alloc((size_t)64*4);
  float* ss    = (float*)alloc((size_t)9216*4);
  if (off > ws_size) return;   // workspace too small: fail loudly (wrong output)

  hipMemsetAsync(base, 0, zlen, stream);

  auto wcv = [&](const float* s, bf16* d, int N, int Cin, int st, int so){
    long total = (long)N*Cin*9;
    kwconv<<<dim3((unsigned)((total+255)/256)), dim3(256), 0, stream>>>(s, d, N, Cin, st, so);
  };
  wcv(mkw1, WmkA, 1024, 2048, 18432, 0);
  wcv(mkw2, WmkB, 512, 1024, 9216, 0);
  wcv(h0w1, Whc1, 1024, 2048, 18432, 0);
  wcv(c0w1, Whc1 + (size_t)1024*18432, 1024, 2048, 18432, 0);
  wcv(h0w2, Wh0b, 512, 1024, 9216, 0);
  wcv(c0w2, Wc0b, 512, 1024, 9216, 0);
  wcv(lstmw, Wx, 2048, 2048, 23040, 0);
  wcv(lstmw, Whh, 2048, 512, 23040, 18432);

  kbnprep<<<dim3(18), dim3(256), 0, stream>>>(mkbn1, mkbn2, h0bn1, c0bn1, h0bn2, c0bn2, ss);
  kxtp<<<dim3(28512), dim3(256), 0, stream>>>(x, xtp);

  // mask branch
  kgemm<<<dim3(17,8,2), dim3(256), 0, stream>>>(xtp, WmkA, 2048, 2048, 0, 2156, 18432, 9216, Cb1, 1024, (long)2176*1024);
  kbnpack<<<dim3(8624), dim3(256), 0, stream>>>(Cb1, Cb1 + (size_t)2176*1024, ss+0, ss+1024, 1024, 2156, a1p, 1024);
  kgemm<<<dim3(17,4,2), dim3(256), 0, stream>>>(a1p, WmkB, 1024, 1024, 0, 2156, 9216, 4608, Cb2, 512, (long)2176*512);
  kbnpack<<<dim3(4312), dim3(256), 0, stream>>>(Cb2, Cb2 + (size_t)2176*512, ss+2048, ss+2560, 512, 2156, a2p, 512);
  kmask3<<<dim3(2156), dim3(256), 0, stream>>>(a2p, mkw3, maskb, dout + 246);

  // mx (in place), mean_x, att_fea
  kmxp<<<dim3(28512), dim3(256), 0, stream>>>(xtp, maskb);
  kmxmp<<<dim3(1296), dim3(256), 0, stream>>>(xtp, mxmp);
  kattfea<<<dim3(44), dim3(256), 0, stream>>>(x, wf, maskb, attf);

  // Gx = conv_Wx(mx) for all (b,t): splitK2 partials then reduce
  kgemm<<<dim3(17,16,2), dim3(256), 0, stream>>>(xtp, Wx, 2048, 2048, 0, 2156, 18432, 9216, Gx, 2048, (long)2176*2048);
  kredgx<<<dim3(17248), dim3(256), 0, stream>>>(Gx);

  // h0 / c0 branches (combined conv1, then two layer-2 convs)
  kgemm<<<dim3(1,16,16), dim3(256), 0, stream>>>(mxmp, Whc1, 2048, 2048, 0, 98, 18432, 1152, Pbuf, 2048, (long)98*2048);
  kredpack<<<dim3(784), dim3(256), 0, stream>>>(Pbuf, 16, (long)98*2048, 2048, ss+3072, ss+5120, hc1p, 2048, nullptr, nullptr, 0);
  kgemm<<<dim3(1,4,16), dim3(256), 0, stream>>>(hc1p, Wh0b, 1024, 2048, 0, 98, 9216, 576, Pbuf, 512, (long)98*512);
  kgemm<<<dim3(1,4,16), dim3(256), 0, stream>>>(hc1p, Wc0b, 1024, 2048, 1024, 98, 9216, 576, Pbuf + (size_t)16*98*512, 512, (long)98*512);
  kredpack<<<dim3(196), dim3(256), 0, stream>>>(Pbuf, 16, (long)98*512, 512, ss+7168, ss+7680, hp, 512, nullptr, hmean, 1);
  kredpack<<<dim3(196), dim3(256), 0, stream>>>(Pbuf + (size_t)16*98*512, 16, (long)98*512, 512, ss+8192, ss+8704, nullptr, 0, cstate, nullptr, 2);

  // LSTM scan, T=22
  for (int t=0;t<22;++t){
    int cur = t & 1, nxt = cur ^ 1;
    kaw<<<dim3(1), dim3(64), 0, stream>>>(hmean + cur*1024, hmean + nxt*1024, wh, attf, awbuf, dout + 202);
    k1<<<dim3(784), dim3(256), 0, stream>>>(Gx, awbuf, lstmb, gatesx);
    kgemm<<<dim3(1,16,8), dim3(256), 0, stream>>>(hp, Whh, 512, 512, 0, 98, 4608, 576, Pbuf, 2048, (long)98*2048);
    k3<<<dim3(196), dim3(256), 0, stream>>>(gatesx, Pbuf, cstate, hp, hmean + nxt*1024, outsS);
  }
  kfinal<<<dim3(1), dim3(256), 0, stream>>>(outsS, fc_w, fc_b, dout);
}

// Round 2
// 1898.859 us; speedup vs baseline: 2.1467x; 2.1467x over previous
//
#include <hip/hip_runtime.h>
#include <hip/hip_bf16.h>

using bf16 = __hip_bfloat16;
typedef __attribute__((ext_vector_type(8))) short s8v;   // 8 bf16 (4 VGPR)
typedef __attribute__((ext_vector_type(4))) float f4v;   // 4 fp32 acc

static __device__ __forceinline__ float bf2f(bf16 v){ return __bfloat162float(v); }
static __device__ __forceinline__ bf16 f2bf(float v){ return __float2bfloat16(v); }
static __device__ __forceinline__ float sigm(float x){ return 1.f/(1.f+expf(-x)); }

typedef __attribute__((address_space(1))) unsigned int u32_glb;
typedef __attribute__((address_space(3))) unsigned int u32_lds;
static __device__ __forceinline__ void gld16(const void* g, void* l){
  __builtin_amdgcn_global_load_lds((const u32_glb*)(unsigned long long)g,
                                   (u32_lds*)l, 16, 0, 0);
}

// ---------------------------------------------------------------------------
// Conv-GEMM: A = padded channel-last images (IMG,9x9,rowC) bf16, im2col via
// per-lane gather (k = tap*Cin + ci). B = weights [N][9*Cin] bf16.
// 128x128 tile, BK=64, 4 waves (2x2), double-buffered LDS staged with
// global_load_lds(16B); XOR chunk swizzle (both sides) for conflict-free
// ds_read_b128. One __syncthreads per K-step (2-phase pipeline).
// ---------------------------------------------------------------------------
__global__ __launch_bounds__(256)
void kgemm(const bf16* __restrict__ Ab, const bf16* __restrict__ Bw,
           int Cin, int rowC, int chOff, int Mvalid, int Ktot, int kLen,
           float* __restrict__ Cout, int ldC, long sliceStride)
{
  __shared__ __align__(16) bf16 As[2][8192];
  __shared__ __align__(16) bf16 Bs[2][8192];
  const int tid = threadIdx.x;
  const int m0 = blockIdx.x*128, n0 = blockIdx.y*128;
  const int k0 = blockIdx.z*kLen;

  const int lane = tid & 63;
  const int wv = tid >> 6;
  const int lr = lane >> 3;                 // row-in-8 within a stage call
  const int c8 = (lane & 7) ^ lr;           // source 16B-chunk (XOR swizzle)

  long aBase[4], bBase[4];
  #pragma unroll
  for (int q=0;q<4;++q){
    int r = wv*32 + q*8 + lr;
    int m = m0 + r; if (m > Mvalid-1) m = Mvalid-1;
    int img = m/49; int hw = m - img*49; int h = hw/7; int w = hw - h*7;
    long pix = (long)img*81 + (h+1)*9 + (w+1);
    aBase[q] = pix*(long)rowC + chOff + c8*8;
    bBase[q] = (long)(n0 + r)*Ktot + k0 + c8*8;
  }

  f4v acc[4][4] = {};
  const int wr = (wv>>1)*64, wc = (wv&1)*64;
  const int fr = lane & 15, fg = lane >> 4;
  const int nSteps = kLen >> 6;

  int tapN = k0 / Cin, ciN = k0 - tapN*Cin;   // k-decomposition of next stage

  auto stage = [&](int nb, long aOff, long bOff){
    #pragma unroll
    for (int q=0;q<4;++q){
      gld16(Ab + aBase[q] + aOff, &As[nb][(wv*4+q)*512]);
      gld16(Bw + bBase[q] + bOff, &Bs[nb][(wv*4+q)*512]);
    }
  };

  // prologue
  stage(0, (long)(tapN + 6*(tapN/3) - 10)*rowC + ciN, 0);
  ciN += 64; if (ciN >= Cin){ ciN = 0; ++tapN; }
  __syncthreads();

  int cur = 0;
  for (int ks=0; ks<nSteps; ++ks){
    if (ks+1 < nSteps){
      stage(cur^1, (long)(tapN + 6*(tapN/3) - 10)*rowC + ciN, (long)(ks+1)*64);
      ciN += 64; if (ciN >= Cin){ ciN = 0; ++tapN; }
    }
    #pragma unroll
    for (int kk=0;kk<2;++kk){
      s8v af[4], bfr[4];
      #pragma unroll
      for (int mt=0;mt<4;++mt){
        int r = wr+mt*16+fr;
        af[mt]  = *(const s8v*)(&As[cur][(r*64 + kk*32 + fg*8) ^ ((r&7)<<3)]);
      }
      #pragma unroll
      for (int nt=0;nt<4;++nt){
        int r = wc+nt*16+fr;
        bfr[nt] = *(const s8v*)(&Bs[cur][(r*64 + kk*32 + fg*8) ^ ((r&7)<<3)]);
      }
      #pragma unroll
      for (int mt=0;mt<4;++mt)
        #pragma unroll
        for (int nt=0;nt<4;++nt)
          acc[mt][nt] = __builtin_amdgcn_mfma_f32_16x16x32_bf16(af[mt], bfr[nt], acc[mt][nt], 0,0,0);
    }
    __syncthreads();   // drains vmcnt(0): next buffer staged; all reads of cur done
    cur ^= 1;
  }

  float* Cp = Cout + (long)blockIdx.z*sliceStride;
  #pragma unroll
  for (int mt=0;mt<4;++mt){
    #pragma unroll
    for (int j=0;j<4;++j){
      int m = m0 + wr + mt*16 + fg*4 + j;        // C/D: row=(lane>>4)*4+reg
      if (m < Mvalid){
        float* row = Cp + (long)m*ldC + n0 + wc;
        #pragma unroll
        for (int nt=0;nt<4;++nt) row[nt*16 + fr] = acc[mt][nt][j];   // col=lane&15
      }
    }
  }
}

// fp32 [co][ci][3][3] -> bf16 [co][tap*Cin+ci], LDS-transposed (coalesced both sides)
__global__ void kwconv(const float* __restrict__ src, bf16* __restrict__ dst,
                       int Cin, int cbN, int srcStride, int srcOff)
{
  __shared__ float s[2304];
  int n = blockIdx.x / cbN, cb = blockIdx.x - n*cbN;
  int tid = threadIdx.x;
  const float* sp = src + (long)n*srcStride + srcOff + cb*2304;
  for (int i=tid; i<2304; i+=256) s[i] = sp[i];
  __syncthreads();
  bf16* dp = dst + (long)n*(9*Cin) + cb*256;
  #pragma unroll
  for (int k=0;k<9;++k)
    dp[(long)k*Cin + tid] = f2bf(s[tid*9 + k]);
}

// BN scale/shift precompute for the 6 param sets
__global__ void kbnprep(const float* mk1, const float* mk2, const float* hb1,
                        const float* cb1, const float* hb2, const float* cb2,
                        float* ss)
{
  int i = blockIdx.x*256 + threadIdx.x;
  if (i >= 4608) return;
  const float* p; int C, c, so, sho;
  if (i < 1024)      { p=mk1; C=1024; c=i;       so=0;    sho=1024; }
  else if (i < 1536) { p=mk2; C=512;  c=i-1024;  so=2048; sho=2560; }
  else if (i < 2560) { p=hb1; C=1024; c=i-1536;  so=3072; sho=5120; }
  else if (i < 3584) { p=cb1; C=1024; c=i-2560;  so=4096; sho=6144; }
  else if (i < 4096) { p=hb2; C=512;  c=i-3584;  so=7168; sho=7680; }
  else               { p=cb2; C=512;  c=i-4096;  so=8192; sho=8704; }
  float g=p[c], b=p[C+c], m=p[2*C+c], v=p[3*C+c];
  float s = g * rsqrtf(v + 1e-5f);
  ss[so + c] = s;
  ss[sho + c] = b - m*s;
}

// x (2,2048,22,7,7) fp32 -> xtp (44,81,2048) bf16 padded channel-last (LDS transpose)
__global__ void ktrans(const float* __restrict__ x, bf16* __restrict__ xtp)
{
  __shared__ float s[64*49];
  int bt = blockIdx.x >> 5;
  int cb = blockIdx.x & 31;
  int b = bt/22, t = bt - b*22;
  int tid = threadIdx.x;
  const float* xp = x + ((long)(b*2048 + cb*64)*22 + t)*49;
  for (int i=tid; i<64*49; i+=256){
    int ci = i/49, hw = i - ci*49;
    s[i] = xp[(long)ci*(22*49) + hw];
  }
  __syncthreads();
  bf16* op = xtp + (long)bt*81*2048 + cb*64;
  for (int j=tid; j<81*64; j+=256){
    int hwp = j>>6, ci = j&63;
    int h9 = hwp/9, w9 = hwp - h9*9;
    float v = 0.f;
    if (h9>=1&&h9<=7&&w9>=1&&w9<=7) v = s[ci*49 + (h9-1)*7 + (w9-1)];
    op[(long)hwp*2048 + ci] = f2bf(v);
  }
}

// reduce S slices + BN + relu -> padded channel-last bf16 image
__global__ void kbnpack(const float* __restrict__ P, int slices, long sstride,
                        const float* __restrict__ scale, const float* __restrict__ shift,
                        int N, int Mvalid, bf16* __restrict__ outImg, int outRowC)
{
  int idx = blockIdx.x*256 + threadIdx.x;
  if (idx >= Mvalid*N) return;
  int m = idx / N, n = idx - m*N;
  float v = 0.f;
  for (int s=0;s<slices;++s) v += P[(long)s*sstride + idx];
  v = fmaxf(fmaf(v, scale[n], shift[n]), 0.f);
  int img = m/49, hw = m - img*49;
  int h = hw/7, w = hw - h*7;
  outImg[((long)img*81 + (h+1)*9 + (w+1))*outRowC + n] = f2bf(v);
}

// mask conv3 (512->1) + sigmoid
__global__ void kmask3(const bf16* __restrict__ a2p, const float* __restrict__ w3,
                       float* __restrict__ maskb, float* __restrict__ outMask)
{
  __shared__ float red[256];
  int bid = blockIdx.x;                 // 2156 = bt*49+hw
  int bt = bid/49, hw = bid - bt*49;
  int h = hw/7, w = hw - h*7;
  int tid = threadIdx.x;
  float s = 0.f;
  for (int k = tid; k < 4608; k += 256){
    int tap = k >> 9, ci = k & 511;
    int pix = (h + tap/3)*9 + (w + (tap - (tap/3)*3));
    s += bf2f(a2p[((long)bt*81 + pix)*512 + ci]) * w3[ci*9 + tap];
  }
  red[tid] = s; __syncthreads();
  for (int off=128; off>0; off>>=1){ if (tid<off) red[tid]+=red[tid+off]; __syncthreads(); }
  if (tid==0){
    float mv = 1.f/(1.f + expf(-red[0]));
    maskb[bid] = mv;
    outMask[bid] = mv;
  }
}

// scale xtp in place by mask (borders stay 0)
__global__ void kmxp(bf16* __restrict__ xtp, const float* __restrict__ maskb)
{
  int idx = blockIdx.x*256 + threadIdx.x;
  int rest = idx >> 11;
  int hwp = rest % 81;
  int bt = rest / 81;
  int h9 = hwp/9, w9 = hwp - h9*9;
  if (h9<1||h9>7||w9<1||w9>7) return;
  float mv = maskb[bt*49 + (h9-1)*7 + (w9-1)];
  xtp[idx] = f2bf(bf2f(xtp[idx]) * mv);
}

// mean over T -> mxmp (2,81,2048) bf16
__global__ void kmxmp(const bf16* __restrict__ mxp, bf16* __restrict__ mxmp)
{
  int idx = blockIdx.x*256 + threadIdx.x;
  int ci = idx & 2047;
  int rest = idx >> 11;
  int hwp = rest % 81;
  int b = rest / 81;
  float s = 0.f;
  #pragma unroll
  for (int t=0;t<22;++t)
    s += bf2f(mxp[((long)(b*22+t)*81 + hwp)*2048 + ci]);
  mxmp[idx] = f2bf(s * (1.f/22.f));
}

// att_fea[b][t] = (1/49) sum_{c,hw} mask*x*wf
__global__ void kattfea(const float* __restrict__ x, const float* __restrict__ wf,
                        const float* __restrict__ maskb, float* __restrict__ attf)
{
  __shared__ float red[256];
  int bt = blockIdx.x; int b = bt/22, t = bt - b*22;
  int tid = threadIdx.x;
  float s = 0.f;
  for (int c=tid;c<2048;c+=256){
    const float* xp = x + ((long)(b*2048+c)*22 + t)*49;
    const float* mp = maskb + bt*49;
    float inner = 0.f;
    #pragma unroll
    for (int hw=0;hw<49;++hw) inner += mp[hw]*xp[hw];
    s += inner * wf[c];
  }
  red[tid] = s; __syncthreads();
  for (int off=128; off>0; off>>=1){ if (tid<off) red[tid]+=red[tid+off]; __syncthreads(); }
  if (tid==0) attf[bt] = red[0] * (1.f/49.f);
}

// sum S slices into slice 0
__global__ void ksum(float* __restrict__ P, int slices, long sstride, long total)
{
  long idx = (long)blockIdx.x*256 + threadIdx.x;
  if (idx >= total) return;
  float v = P[idx];
  for (int s=1;s<slices;++s) v += P[(long)s*sstride + idx];
  P[idx] = v;
}

// reduce splitK slices + BN + relu; mode0: pack padded img; mode1: + hmean; mode2: flat fp32
__global__ void kredpack(const float* __restrict__ P, int slices, long sstride,
                         int N, const float* __restrict__ scale, const float* __restrict__ shift,
                         bf16* __restrict__ outImg, int outRowC,
                         float* __restrict__ outFlat, float* __restrict__ hmeanOut, int mode)
{
  int idx = blockIdx.x*256 + threadIdx.x;   // 98*N exact
  int m = idx / N, n = idx - m*N;
  float v = 0.f;
  for (int s=0;s<slices;++s) v += P[(long)s*sstride + idx];
  v = fmaxf(fmaf(v, scale[n], shift[n]), 0.f);
  if (mode == 2){ outFlat[idx] = v; return; }
  int img = m/49, hw = m - img*49;
  int h = hw/7, w = hw - h*7;
  outImg[((long)img*81 + (h+1)*9 + (w+1))*outRowC + n] = f2bf(v);
  if (mode == 1) atomicAdd(&hmeanOut[img*512 + n], v*(1.f/49.f));
}

// merged: attention softmax (per-block, redundant) + gates_x weighted sum
__global__ void k1aw(const float* __restrict__ Gx, const float* __restrict__ hmC,
                     float* __restrict__ hmN, const float* __restrict__ wh,
                     const float* __restrict__ attf, const float* __restrict__ lstmb,
                     float* __restrict__ gatesx, float* __restrict__ awsOut)
{
  __shared__ float red[256];
  __shared__ float aw[22];
  int tid = threadIdx.x;
  int bid = blockIdx.x;                 // 784 blocks: 392 per b
  int b = bid / 392;
  float s = 0.f;
  for (int c=tid;c<512;c+=256) s += hmC[b*512+c]*wh[c];
  red[tid] = s; __syncthreads();
  for (int off=128; off>0; off>>=1){ if (tid<off) red[tid]+=red[tid+off]; __syncthreads(); }
  if (tid==0){
    float ah = red[0];
    float lo[22]; float mx = -1e30f;
    #pragma unroll
    for (int t=0;t<22;++t){ lo[t] = attf[b*22+t] + ah; mx = fmaxf(mx, lo[t]); }
    float sum=0.f;
    #pragma unroll
    for (int t=0;t<22;++t){ lo[t] = expf(lo[t]-mx); sum += lo[t]; }
    float inv = 1.f/sum;
    #pragma unroll
    for (int t=0;t<22;++t) aw[t] = lo[t]*inv;
  }
  __syncthreads();
  int idx = bid*256 + tid;
  int n = idx & 2047;
  int rest = idx >> 11;
  int hw = rest % 49;
  float g = lstmb[n];
  const float* gp = Gx + ((long)b*22*49 + hw)*2048 + n;
  #pragma unroll
  for (int t=0;t<22;++t) g += aw[t] * gp[(long)t*49*2048];
  gatesx[idx] = g;
  if ((bid==0 || bid==392) && tid<22) awsOut[b*22+tid] = aw[tid];
  if (bid==0) for (int i=tid;i<1024;i+=256) hmN[i] = 0.f;
}

// LSTM pointwise: gates = gates_x + 8 Wh-partials; update c, h; accum means
__global__ void k3(const float* __restrict__ gatesx, const float* __restrict__ P,
                   float* __restrict__ cstate, bf16* __restrict__ hp,
                   float* __restrict__ hmN, float* __restrict__ outs)
{
  int idx = blockIdx.x*256 + threadIdx.x;   // 2*49*512 exact
  int c = idx & 511;
  int rest = idx >> 9;
  int hw = rest % 49;
  int b = rest / 49;
  long mbase = (long)(b*49 + hw)*2048;
  float gi = gatesx[mbase + c],        gf = gatesx[mbase + 512 + c],
        go = gatesx[mbase + 1024 + c], gg = gatesx[mbase + 1536 + c];
  #pragma unroll
  for (int s=0;s<8;++s){
    const float* Ps = P + (long)s*98*2048 + mbase;
    gi += Ps[c]; gf += Ps[512+c]; go += Ps[1024+c]; gg += Ps[1536+c];
  }
  float iv = sigm(gi), fv = sigm(gf), ov = sigm(go), gv = tanhf(gg);
  float cn = fv*cstate[idx] + iv*gv;
  cstate[idx] = cn;
  float h2 = ov*tanhf(cn);
  int h = hw/7, w = hw - h*7;
  hp[((long)b*81 + (h+1)*9 + (w+1))*512 + c] = f2bf(h2);
  atomicAdd(&hmN[b*512 + c], h2*(1.f/49.f));
  atomicAdd(&outs[b*512 + c], h2*(1.f/(49.f*22.f)));
}

// final fc + zero losses
__global__ void kfinal(const float* __restrict__ outs, const float* __restrict__ fc_w,
                       const float* __restrict__ fc_b, float* __restrict__ dout)
{
  int tid = threadIdx.x;
  for (int o=tid;o<202;o+=256){
    int b = o/101, j = o - b*101;
    float s = fc_b[j];
    const float* wrow = fc_w + j*512;
    const float* ov = outs + b*512;
    for (int c=0;c<512;++c) s += ov[c]*wrow[c];
    dout[o] = s;
  }
  if (tid==0){ dout[2402]=0.f; dout[2403]=0.f; }
}

extern "C" void kernel_launch(void* const* d_in, const int* in_sizes, int n_in,
                              void* d_out, int out_size, void* d_ws, size_t ws_size,
                              hipStream_t stream)
{
  (void)in_sizes; (void)n_in; (void)out_size;
  const float* x     = (const float*)d_in[0];
  const float* wf    = (const float*)d_in[1];
  const float* wh    = (const float*)d_in[2];
  const float* fc_w  = (const float*)d_in[3];
  const float* fc_b  = (const float*)d_in[4];
  const float* h0w1  = (const float*)d_in[5];
  const float* h0bn1 = (const float*)d_in[6];
  const float* h0w2  = (const float*)d_in[7];
  const float* h0bn2 = (const float*)d_in[8];
  const float* c0w1  = (const float*)d_in[9];
  const float* c0bn1 = (const float*)d_in[10];
  const float* c0w2  = (const float*)d_in[11];
  const float* c0bn2 = (const float*)d_in[12];
  const float* mkw1  = (const float*)d_in[13];
  const float* mkbn1 = (const float*)d_in[14];
  const float* mkw2  = (const float*)d_in[15];
  const float* mkbn2 = (const float*)d_in[16];
  const float* mkw3  = (const float*)d_in[17];
  const float* lstmw = (const float*)d_in[18];
  const float* lstmb = (const float*)d_in[19];
  float* dout = (float*)d_out;

  char* base = (char*)d_ws;
  size_t off = 0;
  auto alloc = [&](size_t bytes)->void*{
    void* p = base + off;
    off = (off + bytes + 255) & ~(size_t)255;
    return p;
  };
  // --- zero span (memset once per call) ---
  bf16*  a1p   = (bf16*) alloc((size_t)44*81*1024*2);
  bf16*  a2p   = (bf16*) alloc((size_t)44*81*512*2);
  bf16*  hc1p  = (bf16*) alloc((size_t)2*81*2048*2);
  bf16*  hp    = (bf16*) alloc((size_t)2*81*512*2);
  float* hmean = (float*)alloc((size_t)2*1024*4);
  float* outsS = (float*)alloc((size_t)1024*4);
  size_t zlen = off;
  // --- rest ---
  bf16*  WmkA  = (bf16*) alloc((size_t)1024*18432*2);
  bf16*  WmkB  = (bf16*) alloc((size_t)512*9216*2);
  bf16*  Whc1  = (bf16*) alloc((size_t)2048*18432*2);
  bf16*  Wh0b  = (bf16*) alloc((size_t)512*9216*2);
  bf16*  Wc0b  = (bf16*) alloc((size_t)512*9216*2);
  bf16*  Wx    = (bf16*) alloc((size_t)2048*18432*2);
  bf16*  Whh   = (bf16*) alloc((size_t)2048*4608*2);
  bf16*  xtp   = (bf16*) alloc((size_t)44*81*2048*2);
  bf16*  mxmp  = (bf16*) alloc((size_t)2*81*2048*2);
  float* Gx    = (float*)alloc((size_t)2*2176*2048*4);
  float* Cb1   = (float*)alloc((size_t)4*2176*1024*4);
  float* Cb2   = (float*)alloc((size_t)4*2176*512*4);
  float* Pbuf  = (float*)alloc((size_t)16*98*2048*4);
  float* maskb = (float*)alloc((size_t)2156*4);
  float* gatesx= (float*)alloc((size_t)98*2048*4);
  float* attf  = (float*)alloc((size_t)64*4);
  float* cstate= (float*)alloc((size_t)98*512*4);
  float* ss    = (float*)alloc((size_t)9216*4);
  if (off > ws_size) return;   // workspace too small: fail loudly

  hipMemsetAsync(base, 0, zlen, stream);

  auto wcv = [&](const float* s, bf16* d, int N, int Cin, int st, int so){
    kwconv<<<dim3((unsigned)(N*(Cin/256))), dim3(256), 0, stream>>>(s, d, Cin, Cin/256, st, so);
  };
  wcv(mkw1, WmkA, 1024, 2048, 18432, 0);
  wcv(mkw2, WmkB, 512, 1024, 9216, 0);
  wcv(h0w1, Whc1, 1024, 2048, 18432, 0);
  wcv(c0w1, Whc1 + (size_t)1024*18432, 1024, 2048, 18432, 0);
  wcv(h0w2, Wh0b, 512, 1024, 9216, 0);
  wcv(c0w2, Wc0b, 512, 1024, 9216, 0);
  wcv(lstmw, Wx, 2048, 2048, 23040, 0);
  wcv(lstmw, Whh, 2048, 512, 23040, 18432);

  kbnprep<<<dim3(18), dim3(256), 0, stream>>>(mkbn1, mkbn2, h0bn1, c0bn1, h0bn2, c0bn2, ss);
  ktrans<<<dim3(1408), dim3(256), 0, stream>>>(x, xtp);

  // mask branch (k-split 4)
  kgemm<<<dim3(17,8,4), dim3(256), 0, stream>>>(xtp, WmkA, 2048, 2048, 0, 2156, 18432, 4608, Cb1, 1024, (long)2176*1024);
  kbnpack<<<dim3(8624), dim3(256), 0, stream>>>(Cb1, 4, (long)2176*1024, ss+0, ss+1024, 1024, 2156, a1p, 1024);
  kgemm<<<dim3(17,4,4), dim3(256), 0, stream>>>(a1p, WmkB, 1024, 1024, 0, 2156, 9216, 2304, Cb2, 512, (long)2176*512);
  kbnpack<<<dim3(4312), dim3(256), 0, stream>>>(Cb2, 4, (long)2176*512, ss+2048, ss+2560, 512, 2156, a2p, 512);
  kmask3<<<dim3(2156), dim3(256), 0, stream>>>(a2p, mkw3, maskb, dout + 246);

  // mx (in place), mean_x, att_fea
  kmxp<<<dim3(28512), dim3(256), 0, stream>>>(xtp, maskb);
  kmxmp<<<dim3(1296), dim3(256), 0, stream>>>(xtp, mxmp);
  kattfea<<<dim3(44), dim3(256), 0, stream>>>(x, wf, maskb, attf);

  // Gx = conv_Wx(mx) for all (b,t): splitK2 + reduce
  kgemm<<<dim3(17,16,2), dim3(256), 0, stream>>>(xtp, Wx, 2048, 2048, 0, 2156, 18432, 9216, Gx, 2048, (long)2176*2048);
  ksum<<<dim3(17248), dim3(256), 0, stream>>>(Gx, 2, (long)2176*2048, (long)2156*2048);

  // h0 / c0 branches
  kgemm<<<dim3(1,16,16), dim3(256), 0, stream>>>(mxmp, Whc1, 2048, 2048, 0, 98, 18432, 1152, Pbuf, 2048, (long)98*2048);
  kredpack<<<dim3(784), dim3(256), 0, stream>>>(Pbuf, 16, (long)98*2048, 2048, ss+3072, ss+5120, hc1p, 2048, nullptr, nullptr, 0);
  kgemm<<<dim3(1,4,16), dim3(256), 0, stream>>>(hc1p, Wh0b, 1024, 2048, 0, 98, 9216, 576, Pbuf, 512, (long)98*512);
  kgemm<<<dim3(1,4,16), dim3(256), 0, stream>>>(hc1p, Wc0b, 1024, 2048, 1024, 98, 9216, 576, Pbuf + (size_t)16*98*512, 512, (long)98*512);
  kredpack<<<dim3(196), dim3(256), 0, stream>>>(Pbuf, 16, (long)98*512, 512, ss+7168, ss+7680, hp, 512, nullptr, hmean, 1);
  kredpack<<<dim3(196), dim3(256), 0, stream>>>(Pbuf + (size_t)16*98*512, 16, (long)98*512, 512, ss+8192, ss+8704, nullptr, 0, cstate, nullptr, 2);

  // LSTM scan, T=22
  for (int t=0;t<22;++t){
    int cur = t & 1, nxt = cur ^ 1;
    k1aw<<<dim3(784), dim3(256), 0, stream>>>(Gx, hmean + cur*1024, hmean + nxt*1024, wh, attf, lstmb, gatesx, dout + 202);
    kgemm<<<dim3(1,16,8), dim3(256), 0, stream>>>(hp, Whh, 512, 512, 0, 98, 4608, 576, Pbuf, 2048, (long)98*2048);
    k3<<<dim3(196), dim3(256), 0, stream>>>(gatesx, Pbuf, cstate, hp, hmean + nxt*1024, outsS);
  }
  kfinal<<<dim3(1), dim3(256), 0, stream>>>(outsS, fc_w, fc_b, dout);
}